// Round 4
// baseline (251.478 us; speedup 1.0000x reference)
//
#include <hip/hip_runtime.h>
#include <hip/hip_bf16.h>
#include <stdint.h>

typedef __bf16 bf16;
typedef __bf16 bf16x8 __attribute__((ext_vector_type(8)));
typedef __bf16 bf16x4 __attribute__((ext_vector_type(4)));
typedef float  f32x4  __attribute__((ext_vector_type(4)));
typedef float  f32x16 __attribute__((ext_vector_type(16)));

#define S_LEN  2048
#define NH     16
#define DKV    64
#define DMODEL 1024
#define LOG2E  1.4426950408889634f

// ---------------------------------------------------------------------------
// async global->LDS 16B copy. LDS dest is wave-uniform base + lane*16.
// ---------------------------------------------------------------------------
__device__ __forceinline__ void async_load16(const void* g, void* l) {
  __builtin_amdgcn_global_load_lds(
      (const __attribute__((address_space(1))) uint32_t*)(uintptr_t)g,
      (__attribute__((address_space(3))) uint32_t*)(uintptr_t)l,
      16, 0, 0);
}

// ---------------------------------------------------------------------------
// Cast q/k/v fp32 -> bf16, 8 elements/thread. grid (2048, 3)
// ---------------------------------------------------------------------------
__global__ void cast_qkv(const float* __restrict__ q, const float* __restrict__ k,
                         const float* __restrict__ v,
                         bf16* __restrict__ qo, bf16* __restrict__ ko, bf16* __restrict__ vo)
{
  int z = blockIdx.y;
  const float* in = (z == 0) ? q : (z == 1) ? k : v;
  bf16* out = (z == 0) ? qo : (z == 1) ? ko : vo;
  int i = blockIdx.x * 256 + threadIdx.x;
  const float4* in4 = (const float4*)in;
  float4 a = in4[2 * i];
  float4 c = in4[2 * i + 1];
  bf16x8 o;
  o[0] = (bf16)a.x; o[1] = (bf16)a.y; o[2] = (bf16)a.z; o[3] = (bf16)a.w;
  o[4] = (bf16)c.x; o[5] = (bf16)c.y; o[6] = (bf16)c.z; o[7] = (bf16)c.w;
  ((bf16x8*)out)[i] = o;
}

// ---------------------------------------------------------------------------
// Transpose-cast W [K=1024][N=1024] fp32 -> Wt bf16 [N][K]. grid (32,32,4), block (32,8)
// ---------------------------------------------------------------------------
__global__ void transpose_w(const float* __restrict__ W0, const float* __restrict__ W1,
                            const float* __restrict__ W2, const float* __restrict__ W3,
                            bf16* __restrict__ T0, bf16* __restrict__ T1,
                            bf16* __restrict__ T2, bf16* __restrict__ T3)
{
  int z = blockIdx.z;
  const float* W = (z == 0) ? W0 : (z == 1) ? W1 : (z == 2) ? W2 : W3;
  bf16* T = (z == 0) ? T0 : (z == 1) ? T1 : (z == 2) ? T2 : T3;
  __shared__ float tile[32][33];
  int n0 = blockIdx.x * 32, k0 = blockIdx.y * 32;
  int tx = threadIdx.x, ty = threadIdx.y;
  for (int i = 0; i < 32; i += 8)
    tile[ty + i][tx] = W[(size_t)(k0 + ty + i) * DMODEL + n0 + tx];
  __syncthreads();
  for (int i = 0; i < 32; i += 8)
    T[(size_t)(n0 + ty + i) * DMODEL + k0 + tx] = (bf16)tile[tx][ty + i];
}

// ---------------------------------------------------------------------------
// GEMM C = A[M,K] * Bt[N,K]^T  (m97 recipe, templated M-tile: TM x 128, BK=32)
// MODE 0: C fp32 row-major [M,N]
// MODE 1: C bf16 head layout [B,NH,S,DKV] for z<2; z==2 writes TRANSPOSED
//         head layout [B,NH,DKV,S] (for attention's V^T staging).
// ---------------------------------------------------------------------------
template<int TM, int MODE>
__global__ __launch_bounds__(256) void gemm_bt(
    const bf16* __restrict__ A0, const bf16* __restrict__ A1, const bf16* __restrict__ A2,
    const bf16* __restrict__ B0, const bf16* __restrict__ B1, const bf16* __restrict__ B2,
    void* __restrict__ C0, void* __restrict__ C1, void* __restrict__ C2,
    int M, int N, int K)
{
  constexpr int MI = TM / 32;           // m-frags per wave
  __shared__ __align__(16) bf16 As[TM * 32];
  __shared__ __align__(16) bf16 Bs[128 * 32];
  int z = blockIdx.z;
  const bf16* A  = (z == 0) ? A0 : (z == 1) ? A1 : A2;
  const bf16* Bt = (z == 0) ? B0 : (z == 1) ? B1 : B2;
  void* C        = (z == 0) ? C0 : (z == 1) ? C1 : C2;

  const int m0 = blockIdx.y * TM;
  const int n0 = blockIdx.x * 128;
  const int tid = threadIdx.x;
  const int lane = tid & 63;
  const int wave = tid >> 6;
  const int wm = (wave >> 1) * (TM / 2);
  const int wn = (wave & 1) * 64;
  const int row = lane & 15;
  const int quad = lane >> 4;

  f32x4 acc[MI][4];
  for (int i = 0; i < MI; ++i)
    for (int j = 0; j < 4; ++j) acc[i][j] = (f32x4){0.f, 0.f, 0.f, 0.f};

  const int nk = K >> 5;
  for (int kt = 0; kt < nk; ++kt) {
    __syncthreads();
    const int kk = kt << 5;
    for (int j = 0; j < TM / 64; ++j) {     // A tile: TM*4 chunks of 16B
      int base = j * 256 + wave * 64;
      int idx = base + lane;
      int r = idx >> 2;
      int cb = (idx & 3) << 4;
      async_load16((const char*)(A + (size_t)(m0 + r) * K + kk) + cb,
                   (char*)As + (size_t)base * 16);
    }
    for (int j = 0; j < 2; ++j) {           // B tile: 512 chunks
      int base = j * 256 + wave * 64;
      int idx = base + lane;
      int r = idx >> 2;
      int cb = (idx & 3) << 4;
      async_load16((const char*)(Bt + (size_t)(n0 + r) * K + kk) + cb,
                   (char*)Bs + (size_t)base * 16);
    }
    __syncthreads();
    bf16x8 af[MI], bfr[4];
    for (int i = 0; i < MI; ++i)
      af[i] = *(const bf16x8*)(As + (wm + i * 16 + row) * 32 + quad * 8);
    for (int j = 0; j < 4; ++j)
      bfr[j] = *(const bf16x8*)(Bs + (wn + j * 16 + row) * 32 + quad * 8);
    for (int i = 0; i < MI; ++i)
      for (int j = 0; j < 4; ++j)
        acc[i][j] = __builtin_amdgcn_mfma_f32_16x16x32_bf16(af[i], bfr[j], acc[i][j], 0, 0, 0);
  }

  if (MODE == 0) {
    float* Cf = (float*)C;
    for (int i = 0; i < MI; ++i)
      for (int j = 0; j < 4; ++j)
        for (int r = 0; r < 4; ++r) {
          int gm = m0 + wm + i * 16 + quad * 4 + r;
          int gn = n0 + wn + j * 16 + row;
          Cf[(size_t)gm * N + gn] = acc[i][j][r];
        }
  } else if (z != 2) {
    bf16* Cb = (bf16*)C;
    for (int i = 0; i < MI; ++i)
      for (int j = 0; j < 4; ++j)
        for (int r = 0; r < 4; ++r) {
          int gm = m0 + wm + i * 16 + quad * 4 + r;
          int gn = n0 + wn + j * 16 + row;
          int b = gm >> 11, s = gm & 2047;
          int h = gn >> 6,  d = gn & 63;
          Cb[(((size_t)(b * NH + h)) * S_LEN + s) * DKV + d] = (bf16)acc[i][j][r];
        }
  } else {
    // V^T head layout [B,NH,DKV,S]; 4 consecutive s per lane -> b64 stores
    bf16* Cb = (bf16*)C;
    for (int i = 0; i < MI; ++i)
      for (int j = 0; j < 4; ++j) {
        int gm = m0 + wm + i * 16 + quad * 4;    // s base (r=0..3 consecutive)
        int gn = n0 + wn + j * 16 + row;
        int b = gm >> 11, s = gm & 2047;
        int h = gn >> 6,  d = gn & 63;
        bf16x4 t;
        for (int r = 0; r < 4; ++r) t[r] = (bf16)acc[i][j][r];
        *(bf16x4*)(Cb + (((size_t)(b * NH + h)) * DKV + d) * S_LEN + s) = t;
      }
  }
}

// ---------------------------------------------------------------------------
// Flash attention v4: S^T = K*Q^T via 32x32x16 MFMA; P stays in REGISTERS
// (C-layout of S^T == A-layout of PV in m; k-axis fixed by a global kv
//  permutation kv_eff(c,hi,u)=(u&3)+8*(u>>2)+4*hi+16*(c&1)+32*(c>>1) applied
//  identically to V^T B-frag reads). Mask folded in as 65th K column.
// grid (S/128, B*NH), block 256 (4 waves, 32 q-rows each). KV tile 64.
// LDS: Ks 8K (XOR-swizzled) + Kext 2K + Vts 8K (swizzled) + lsum 512B = 18.5K
// ---------------------------------------------------------------------------
__global__ __launch_bounds__(256, 4) void attn_kernel(
    const bf16* __restrict__ Qh, const bf16* __restrict__ Kh, const bf16* __restrict__ Vth,
    const float* __restrict__ mask, bf16* __restrict__ ctx)
{
  __shared__ __align__(16) bf16 Ks[64 * 64];    // [kv][d] XOR-swizzled
  __shared__ __align__(16) bf16 Kext[64 * 16];  // [kv][16]: col0 = 8*mask, rest 0
  __shared__ __align__(16) bf16 Vts[64 * 64];   // [d][kv] XOR-swizzled
  __shared__ __align__(16) float lsumS[4 * 32];

  const int bh = blockIdx.y;
  const int b = bh >> 4;
  const int h = bh & 15;
  const int q0 = blockIdx.x * 128;
  const int tid = threadIdx.x;
  const int lane = tid & 63;
  const int wave = tid >> 6;
  const int ln = lane & 31;
  const int hi = lane >> 5;
  const float SC2 = 0.125f * LOG2E;

  // hoisted Q B-frags: B[k=d][n=q] = Q[q][d], d = c*16 + hi*8 + u.
  // chunk 4 is the mask column: Q[q][64]=1, Q[q][65..79]=0.
  const int qg = q0 + wave * 32 + ln;
  bf16x8 qf[5];
  {
    const bf16* qrow = Qh + ((size_t)bh * S_LEN + qg) * DKV;
    for (int c = 0; c < 4; ++c)
      qf[c] = *(const bf16x8*)(qrow + c * 16 + hi * 8);
    bf16x8 z;
    for (int u = 0; u < 8; ++u) z[u] = (bf16)0.f;
    if (hi == 0) z[0] = (bf16)1.0f;
    qf[4] = z;
  }

  f32x16 O[2];
  for (int nb = 0; nb < 2; ++nb)
    for (int i = 0; i < 16; ++i) O[nb][i] = 0.f;
  float lsum = 0.f;

  for (int kv0 = 0; kv0 < S_LEN; kv0 += 64) {
    __syncthreads();  // protect Ks/Vts/Kext from previous iteration's readers
    // async staging, swizzle folded into the global source address:
    // LDS chunk idx holds data chunk cc = (idx&7) ^ ((idx>>3)&7) of row idx>>3
    for (int j = 0; j < 2; ++j) {
      int base = j * 256 + wave * 64;       // wave-uniform
      int idx = base + lane;
      int r = idx >> 3;
      int cc = (idx & 7) ^ (r & 7);
      async_load16(Kh + ((size_t)bh * S_LEN + kv0 + r) * DKV + cc * 8,
                   (char*)Ks + (size_t)base * 16);
      async_load16(Vth + ((size_t)bh * DKV + r) * S_LEN + kv0 + cc * 8,
                   (char*)Vts + (size_t)base * 16);
    }
    if (tid < 64) {   // mask column: Kext[kv][0] = 8*mask (x LOG2E/sc2 = 8)
      float m8 = mask[b * S_LEN + kv0 + tid] * 8.0f;
      bf16x8 e0, zz;
      for (int u = 0; u < 8; ++u) { e0[u] = (bf16)0.f; zz[u] = (bf16)0.f; }
      e0[0] = (bf16)m8;
      *(bf16x8*)(Kext + tid * 16)     = e0;
      *(bf16x8*)(Kext + tid * 16 + 8) = zz;
    }
    __syncthreads();

    // S^T = K * Q^T  (A = K[kv][d], m=kv: 2 m-blocks; B = qf; 5 k-chunks)
    f32x16 Sm[2];
    for (int i = 0; i < 16; ++i) { Sm[0][i] = 0.f; Sm[1][i] = 0.f; }
    for (int c = 0; c < 5; ++c) {
      bf16x8 k0, k1;
      if (c < 4) {
        k0 = *(const bf16x8*)(Ks + (ln)      * 64 + (((2 * c + hi) ^ (ln & 7)) << 3));
        k1 = *(const bf16x8*)(Ks + (32 + ln) * 64 + (((2 * c + hi) ^ (ln & 7)) << 3));
      } else {
        k0 = *(const bf16x8*)(Kext + ln * 16 + hi * 8);
        k1 = *(const bf16x8*)(Kext + (32 + ln) * 16 + hi * 8);
      }
      Sm[0] = __builtin_amdgcn_mfma_f32_32x32x16_bf16(k0, qf[c], Sm[0], 0, 0, 0);
      Sm[1] = __builtin_amdgcn_mfma_f32_32x32x16_bf16(k1, qf[c], Sm[1], 0, 0, 0);
    }

    // P in registers -> PV.  A-frag chunk cg: A[u] = exp2(sc2*Sm[cg>>1][(cg&1)*8+u])
    for (int cg = 0; cg < 4; ++cg) {
      int mb = cg >> 1, g = cg & 1;
      bf16x8 ap;
      float ls0 = 0.f;
      for (int u = 0; u < 8; ++u) {
        float p = __builtin_amdgcn_exp2f(Sm[mb][g * 8 + u] * SC2);
        ls0 += p;
        ap[u] = (bf16)p;
      }
      lsum += ls0;
      for (int nb = 0; nb < 2; ++nb) {
        int d = nb * 32 + ln;
        int ch0 = ((2 * g + 4 * mb))     ^ (d & 7);   // kv group u0..3
        int ch1 = ((1 + 2 * g + 4 * mb)) ^ (d & 7);   // kv group u4..7
        bf16x4 lo = *(const bf16x4*)(Vts + d * 64 + ch0 * 8 + hi * 4);
        bf16x4 hv = *(const bf16x4*)(Vts + d * 64 + ch1 * 8 + hi * 4);
        bf16x8 bv;
        for (int u = 0; u < 4; ++u) { bv[u] = lo[u]; bv[u + 4] = hv[u]; }
        O[nb] = __builtin_amdgcn_mfma_f32_32x32x16_bf16(ap, bv, O[nb], 0, 0, 0);
      }
    }
  }

  // row sums: lane's 32 P-slots cover its hi-half of kv; partner has the rest
  float lt = lsum + __shfl_xor(lsum, 32, 64);
  if (lane < 32) lsumS[wave * 32 + lane] = 1.0f / lt;
  __builtin_amdgcn_s_waitcnt(0);  // same-wave LDS RAW

  // epilogue: O reg r is row (r&3)+8*(r>>2)+4*hi, col nb*32+ln
  for (int g = 0; g < 4; ++g) {
    f32x4 ri = *(const f32x4*)(lsumS + wave * 32 + g * 8 + hi * 4);
    for (int nb = 0; nb < 2; ++nb)
      for (int j = 0; j < 4; ++j) {
        int qrow = q0 + wave * 32 + j + 8 * g + 4 * hi;
        float v = O[nb][g * 4 + j] * ri[j];
        ctx[((size_t)b * S_LEN + qrow) * DMODEL + h * DKV + nb * 32 + ln] = (bf16)v;
      }
  }
}

// ---------------------------------------------------------------------------
extern "C" void kernel_launch(void* const* d_in, const int* in_sizes, int n_in,
                              void* d_out, int out_size, void* d_ws, size_t ws_size,
                              hipStream_t stream)
{
  const float* query = (const float*)d_in[0];
  const float* key_  = (const float*)d_in[1];
  const float* value = (const float*)d_in[2];
  const float* mask  = (const float*)d_in[3];
  const float* Wq = (const float*)d_in[4];
  const float* Wk = (const float*)d_in[5];
  const float* Wv = (const float*)d_in[6];
  const float* Wo = (const float*)d_in[7];

  char* ws = (char*)d_ws;
  const size_t MB = (size_t)1 << 20;
  bf16* qb  = (bf16*)(ws + 0 * MB);    // 8MB each
  bf16* kb  = (bf16*)(ws + 8 * MB);
  bf16* vb  = (bf16*)(ws + 16 * MB);
  bf16* wqt = (bf16*)(ws + 24 * MB);   // 2MB each
  bf16* wkt = (bf16*)(ws + 26 * MB);
  bf16* wvt = (bf16*)(ws + 28 * MB);
  bf16* wot = (bf16*)(ws + 30 * MB);
  bf16* qh  = (bf16*)(ws + 32 * MB);   // 8MB each
  bf16* kh  = (bf16*)(ws + 40 * MB);   // [B,NH,S,DKV]
  bf16* vth = (bf16*)(ws + 48 * MB);   // [B,NH,DKV,S] (transposed V)
  bf16* ctx = (bf16*)(ws + 0 * MB);    // reuse qb region (dead after QKV GEMM)

  cast_qkv<<<dim3(2048, 3), 256, 0, stream>>>(query, key_, value, qb, kb, vb);
  transpose_w<<<dim3(32, 32, 4), dim3(32, 8), 0, stream>>>(Wq, Wk, Wv, Wo, wqt, wkt, wvt, wot);
  gemm_bt<128, 1><<<dim3(8, 32, 3), 256, 0, stream>>>(qb, kb, vb, wqt, wkt, wvt,
                                                      (void*)qh, (void*)kh, (void*)vth,
                                                      4096, 1024, 1024);
  attn_kernel<<<dim3(16, 32), 256, 0, stream>>>(qh, kh, vth, mask, ctx);
  gemm_bt<64, 0><<<dim3(8, 64, 1), 256, 0, stream>>>(ctx, ctx, ctx, wot, wot, wot,
                                                     d_out, d_out, d_out,
                                                     4096, 1024, 1024);
}

// Round 5
// 231.387 us; speedup vs baseline: 1.0868x; 1.0868x over previous
//
#include <hip/hip_runtime.h>
#include <hip/hip_bf16.h>
#include <stdint.h>

typedef __bf16 bf16;
typedef __bf16 bf16x8 __attribute__((ext_vector_type(8)));
typedef __bf16 bf16x4 __attribute__((ext_vector_type(4)));
typedef float  f32x4  __attribute__((ext_vector_type(4)));
typedef float  f32x16 __attribute__((ext_vector_type(16)));

#define S_LEN  2048
#define NH     16
#define DKV    64
#define DMODEL 1024
#define LOG2E  1.4426950408889634f

// ---------------------------------------------------------------------------
// async global->LDS 16B copy. LDS dest is wave-uniform base + lane*16.
// ---------------------------------------------------------------------------
__device__ __forceinline__ void async_load16(const void* g, void* l) {
  __builtin_amdgcn_global_load_lds(
      (const __attribute__((address_space(1))) uint32_t*)(uintptr_t)g,
      (__attribute__((address_space(3))) uint32_t*)(uintptr_t)l,
      16, 0, 0);
}

// ---------------------------------------------------------------------------
// Cast q/k/v fp32 -> bf16, 8 elements/thread. grid (2048, 3)
// ---------------------------------------------------------------------------
__global__ void cast_qkv(const float* __restrict__ q, const float* __restrict__ k,
                         const float* __restrict__ v,
                         bf16* __restrict__ qo, bf16* __restrict__ ko, bf16* __restrict__ vo)
{
  int z = blockIdx.y;
  const float* in = (z == 0) ? q : (z == 1) ? k : v;
  bf16* out = (z == 0) ? qo : (z == 1) ? ko : vo;
  int i = blockIdx.x * 256 + threadIdx.x;
  const float4* in4 = (const float4*)in;
  float4 a = in4[2 * i];
  float4 c = in4[2 * i + 1];
  bf16x8 o;
  o[0] = (bf16)a.x; o[1] = (bf16)a.y; o[2] = (bf16)a.z; o[3] = (bf16)a.w;
  o[4] = (bf16)c.x; o[5] = (bf16)c.y; o[6] = (bf16)c.z; o[7] = (bf16)c.w;
  ((bf16x8*)out)[i] = o;
}

// ---------------------------------------------------------------------------
// Transpose-cast W [K=1024][N=1024] fp32 -> Wt bf16 [N][K]. grid (32,32,4), block (32,8)
// ---------------------------------------------------------------------------
__global__ void transpose_w(const float* __restrict__ W0, const float* __restrict__ W1,
                            const float* __restrict__ W2, const float* __restrict__ W3,
                            bf16* __restrict__ T0, bf16* __restrict__ T1,
                            bf16* __restrict__ T2, bf16* __restrict__ T3)
{
  int z = blockIdx.z;
  const float* W = (z == 0) ? W0 : (z == 1) ? W1 : (z == 2) ? W2 : W3;
  bf16* T = (z == 0) ? T0 : (z == 1) ? T1 : (z == 2) ? T2 : T3;
  __shared__ float tile[32][33];
  int n0 = blockIdx.x * 32, k0 = blockIdx.y * 32;
  int tx = threadIdx.x, ty = threadIdx.y;
  for (int i = 0; i < 32; i += 8)
    tile[ty + i][tx] = W[(size_t)(k0 + ty + i) * DMODEL + n0 + tx];
  __syncthreads();
  for (int i = 0; i < 32; i += 8)
    T[(size_t)(n0 + ty + i) * DMODEL + k0 + tx] = (bf16)tile[tx][ty + i];
}

// ---------------------------------------------------------------------------
// GEMM C = A[M,K] * Bt[N,K]^T  (m97 recipe, templated M-tile: TM x 128, BK=32)
// MODE 0: C fp32 row-major [M,N]
// MODE 1: C bf16 head layout [B,NH,S,DKV] for z<2; z==2 writes V in the
//         PV-permuted layout [bh][s/64][ (s%64)/4 ][d][ s%4 ] (see attn).
// ---------------------------------------------------------------------------
template<int TM, int MODE>
__global__ __launch_bounds__(256) void gemm_bt(
    const bf16* __restrict__ A0, const bf16* __restrict__ A1, const bf16* __restrict__ A2,
    const bf16* __restrict__ B0, const bf16* __restrict__ B1, const bf16* __restrict__ B2,
    void* __restrict__ C0, void* __restrict__ C1, void* __restrict__ C2,
    int M, int N, int K)
{
  constexpr int MI = TM / 32;           // m-frags per wave
  __shared__ __align__(16) bf16 As[TM * 32];
  __shared__ __align__(16) bf16 Bs[128 * 32];
  int z = blockIdx.z;
  const bf16* A  = (z == 0) ? A0 : (z == 1) ? A1 : A2;
  const bf16* Bt = (z == 0) ? B0 : (z == 1) ? B1 : B2;
  void* C        = (z == 0) ? C0 : (z == 1) ? C1 : C2;

  const int m0 = blockIdx.y * TM;
  const int n0 = blockIdx.x * 128;
  const int tid = threadIdx.x;
  const int lane = tid & 63;
  const int wave = tid >> 6;
  const int wm = (wave >> 1) * (TM / 2);
  const int wn = (wave & 1) * 64;
  const int row = lane & 15;
  const int quad = lane >> 4;

  f32x4 acc[MI][4];
  for (int i = 0; i < MI; ++i)
    for (int j = 0; j < 4; ++j) acc[i][j] = (f32x4){0.f, 0.f, 0.f, 0.f};

  const int nk = K >> 5;
  for (int kt = 0; kt < nk; ++kt) {
    __syncthreads();
    const int kk = kt << 5;
    for (int j = 0; j < TM / 64; ++j) {     // A tile: TM*4 chunks of 16B
      int base = j * 256 + wave * 64;
      int idx = base + lane;
      int r = idx >> 2;
      int cb = (idx & 3) << 4;
      async_load16((const char*)(A + (size_t)(m0 + r) * K + kk) + cb,
                   (char*)As + (size_t)base * 16);
    }
    for (int j = 0; j < 2; ++j) {           // B tile: 512 chunks
      int base = j * 256 + wave * 64;
      int idx = base + lane;
      int r = idx >> 2;
      int cb = (idx & 3) << 4;
      async_load16((const char*)(Bt + (size_t)(n0 + r) * K + kk) + cb,
                   (char*)Bs + (size_t)base * 16);
    }
    __syncthreads();
    bf16x8 af[MI], bfr[4];
    for (int i = 0; i < MI; ++i)
      af[i] = *(const bf16x8*)(As + (wm + i * 16 + row) * 32 + quad * 8);
    for (int j = 0; j < 4; ++j)
      bfr[j] = *(const bf16x8*)(Bs + (wn + j * 16 + row) * 32 + quad * 8);
    for (int i = 0; i < MI; ++i)
      for (int j = 0; j < 4; ++j)
        acc[i][j] = __builtin_amdgcn_mfma_f32_16x16x32_bf16(af[i], bfr[j], acc[i][j], 0, 0, 0);
  }

  if (MODE == 0) {
    float* Cf = (float*)C;
    for (int i = 0; i < MI; ++i)
      for (int j = 0; j < 4; ++j)
        for (int r = 0; r < 4; ++r) {
          int gm = m0 + wm + i * 16 + quad * 4 + r;
          int gn = n0 + wn + j * 16 + row;
          Cf[(size_t)gm * N + gn] = acc[i][j][r];
        }
  } else if (z != 2) {
    bf16* Cb = (bf16*)C;
    for (int i = 0; i < MI; ++i)
      for (int j = 0; j < 4; ++j)
        for (int r = 0; r < 4; ++r) {
          int gm = m0 + wm + i * 16 + quad * 4 + r;
          int gn = n0 + wn + j * 16 + row;
          int b = gm >> 11, s = gm & 2047;
          int h = gn >> 6,  d = gn & 63;
          Cb[(((size_t)(b * NH + h)) * S_LEN + s) * DKV + d] = (bf16)acc[i][j][r];
        }
  } else {
    // V permuted for attn PV: [bh][tile=s/64][kb=(s%64)/4][d][sr=s%4]
    bf16* Cb = (bf16*)C;
    for (int i = 0; i < MI; ++i)
      for (int j = 0; j < 4; ++j) {
        int gm = m0 + wm + i * 16 + quad * 4;    // s base (r=0..3 consecutive)
        int gn = n0 + wn + j * 16 + row;
        int b = gm >> 11, s = gm & 2047;
        int h = gn >> 6,  d = gn & 63;
        int bh = b * NH + h;
        int tile = s >> 6, kb = (s & 63) >> 2;
        bf16x4 t;
        for (int r = 0; r < 4; ++r) t[r] = (bf16)acc[i][j][r];
        *(bf16x4*)(Cb + ((((size_t)bh * 32 + tile) * 16 + kb) * 64 + d) * 4) = t;
      }
  }
}

// ---------------------------------------------------------------------------
// Flash attention v5: S^T = K*Q^T via 32x32x16 MFMA; P stays in registers.
// KV-split: blockIdx.z selects half the sequence; fp32 partial O + row-sums
// (fixed-max softmax => partials are additive). Mask added post-MFMA via
// broadcast LDS reads. V pre-permuted so PV B-frag b64 reads are 2-way only.
// grid (S/128, B*NH, 2), block 256. LDS = 8K + 8K + 256B -> 4+ blocks/CU.
// ---------------------------------------------------------------------------
__global__ __launch_bounds__(256, 4) void attn_kernel(
    const bf16* __restrict__ Qh, const bf16* __restrict__ Kh, const bf16* __restrict__ Vperm,
    const float* __restrict__ mask, float* __restrict__ Opart, float* __restrict__ Lpart)
{
  __shared__ __align__(16) bf16 Ks[64 * 64];    // [kv][d], chunk XOR-swizzled
  __shared__ __align__(16) bf16 Vts[64 * 64];   // [kb][d][4] linear (permuted)
  __shared__ __align__(16) float masks2[64];

  const int bh = blockIdx.y;
  const int b = bh >> 4;
  const int q0 = blockIdx.x * 128;
  const int zh = blockIdx.z;                    // kv half
  const int tid = threadIdx.x;
  const int lane = tid & 63;
  const int wave = tid >> 6;
  const int ln = lane & 31;
  const int hi = lane >> 5;
  const float SC2 = 0.125f * LOG2E;

  // hoisted Q B-frags: B[k=d][n=q] = Q[q][d], d = c*16 + hi*8 + u
  const int qg = q0 + wave * 32 + ln;
  bf16x8 qf[4];
  {
    const bf16* qrow = Qh + ((size_t)bh * S_LEN + qg) * DKV;
    for (int c = 0; c < 4; ++c)
      qf[c] = *(const bf16x8*)(qrow + c * 16 + hi * 8);
  }

  f32x16 O[2];
  for (int nb = 0; nb < 2; ++nb)
    for (int i = 0; i < 16; ++i) O[nb][i] = 0.f;
  float lsum = 0.f;

  for (int it = 0; it < 16; ++it) {
    const int kv0 = zh * 1024 + it * 64;
    __syncthreads();  // protect Ks/Vts/masks2 from previous iteration's readers
    // K: XOR swizzle folded into global source; V: linear copy of permuted tile
    const bf16* vtile = Vperm + ((size_t)bh * 32 + (kv0 >> 6)) * (64 * 64);
    for (int j = 0; j < 2; ++j) {
      int base = j * 256 + wave * 64;       // wave-uniform
      int idx = base + lane;
      int r = idx >> 3;
      int cc = (idx & 7) ^ (r & 7);
      async_load16(Kh + ((size_t)bh * S_LEN + kv0 + r) * DKV + cc * 8,
                   (char*)Ks + (size_t)base * 16);
      async_load16(vtile + (size_t)idx * 8,
                   (char*)Vts + (size_t)base * 16);
    }
    if (tid < 64) masks2[tid] = mask[b * S_LEN + kv0 + tid] * LOG2E;
    __syncthreads();

    // S^T = K * Q^T  (A = K[kv][d], m=kv: 2 m-blocks; B = qf; 4 k-chunks)
    f32x16 Sm[2];
    for (int i = 0; i < 16; ++i) { Sm[0][i] = 0.f; Sm[1][i] = 0.f; }
    for (int c = 0; c < 4; ++c) {
      bf16x8 k0 = *(const bf16x8*)(Ks + ln * 64        + (((2 * c + hi) ^ (ln & 7)) << 3));
      bf16x8 k1 = *(const bf16x8*)(Ks + (32 + ln) * 64 + (((2 * c + hi) ^ (ln & 7)) << 3));
      Sm[0] = __builtin_amdgcn_mfma_f32_32x32x16_bf16(k0, qf[c], Sm[0], 0, 0, 0);
      Sm[1] = __builtin_amdgcn_mfma_f32_32x32x16_bf16(k1, qf[c], Sm[1], 0, 0, 0);
    }

    // P = exp2(S*SC2 + mask*LOG2E) in registers -> PV
    for (int cg = 0; cg < 4; ++cg) {
      int mb = cg >> 1, g = cg & 1;
      int koff = 32 * mb + 16 * g + 4 * hi;   // this lane's kv base for u0..3
      f32x4 mklo = *(const f32x4*)(masks2 + koff);
      f32x4 mkhi = *(const f32x4*)(masks2 + koff + 8);
      bf16x8 ap;
      float ls0 = 0.f;
      for (int u = 0; u < 4; ++u) {
        float p = __builtin_amdgcn_exp2f(Sm[mb][g * 8 + u] * SC2 + mklo[u]);
        ls0 += p; ap[u] = (bf16)p;
      }
      for (int u = 0; u < 4; ++u) {
        float p = __builtin_amdgcn_exp2f(Sm[mb][g * 8 + 4 + u] * SC2 + mkhi[u]);
        ls0 += p; ap[4 + u] = (bf16)p;
      }
      lsum += ls0;
      int kb0 = hi + 4 * g + 8 * mb;
      for (int nb = 0; nb < 2; ++nb) {
        int d = nb * 32 + ln;
        bf16x4 lo = *(const bf16x4*)(Vts + ((size_t)kb0 * 64 + d) * 4);
        bf16x4 hv = *(const bf16x4*)(Vts + ((size_t)(kb0 + 2) * 64 + d) * 4);
        bf16x8 bv;
        for (int u = 0; u < 4; ++u) { bv[u] = lo[u]; bv[u + 4] = hv[u]; }
        O[nb] = __builtin_amdgcn_mfma_f32_32x32x16_bf16(ap, bv, O[nb], 0, 0, 0);
      }
    }
  }

  // partial row sums: lane covers its hi-half of kv slots; partner has rest
  float lt = lsum + __shfl_xor(lsum, 32, 64);
  if (lane < 32)
    Lpart[((size_t)zh * 32 + bh) * S_LEN + q0 + wave * 32 + ln] = lt;

  // partial O (un-normalized, fp32): Opart[zh][bh][q][d]
  float* ob = Opart + (((size_t)zh * 32 + bh) * S_LEN) * DKV;
  for (int g = 0; g < 4; ++g)
    for (int nb = 0; nb < 2; ++nb)
      for (int j = 0; j < 4; ++j) {
        int qrow = q0 + wave * 32 + j + 8 * g + 4 * hi;
        ob[(size_t)qrow * DKV + nb * 32 + ln] = O[nb][g * 4 + j];
      }
}

// ---------------------------------------------------------------------------
// Combine halves + normalize -> bf16 ctx [B,S,NH*DKV]. grid 4096 x 256.
// ---------------------------------------------------------------------------
__global__ void combine_kernel(const float* __restrict__ Opart,
                               const float* __restrict__ Lpart,
                               bf16* __restrict__ ctx)
{
  int t = blockIdx.x * 256 + threadIdx.x;
  int dg = t & 15;
  int q  = (t >> 4) & 2047;
  int bh = t >> 15;
  int b = bh >> 4, h = bh & 15;
  size_t o0 = ((size_t)bh * S_LEN + q) * DKV + dg * 4;
  size_t o1 = ((size_t)(32 + bh) * S_LEN + q) * DKV + dg * 4;
  f32x4 a = *(const f32x4*)(Opart + o0);
  f32x4 c = *(const f32x4*)(Opart + o1);
  float l = Lpart[(size_t)bh * S_LEN + q] + Lpart[(size_t)(32 + bh) * S_LEN + q];
  float r = 1.0f / l;
  bf16x4 o;
  for (int u = 0; u < 4; ++u) o[u] = (bf16)((a[u] + c[u]) * r);
  *(bf16x4*)(ctx + ((size_t)(b * S_LEN + q)) * DMODEL + h * DKV + dg * 4) = o;
}

// ---------------------------------------------------------------------------
extern "C" void kernel_launch(void* const* d_in, const int* in_sizes, int n_in,
                              void* d_out, int out_size, void* d_ws, size_t ws_size,
                              hipStream_t stream)
{
  const float* query = (const float*)d_in[0];
  const float* key_  = (const float*)d_in[1];
  const float* value = (const float*)d_in[2];
  const float* mask  = (const float*)d_in[3];
  const float* Wq = (const float*)d_in[4];
  const float* Wk = (const float*)d_in[5];
  const float* Wv = (const float*)d_in[6];
  const float* Wo = (const float*)d_in[7];

  char* ws = (char*)d_ws;
  const size_t MB = (size_t)1 << 20;
  // phase 1: casts/transposes           phase 2: attn      phase 3: combine/out
  bf16* qb    = (bf16*)(ws + 0 * MB);   // 8MB each; region 0..32 becomes Opart
  bf16* kb    = (bf16*)(ws + 8 * MB);
  bf16* vb    = (bf16*)(ws + 16 * MB);
  bf16* wqt   = (bf16*)(ws + 24 * MB);  // 2MB each (dead after QKV GEMM)
  bf16* wkt   = (bf16*)(ws + 26 * MB);
  bf16* wvt   = (bf16*)(ws + 28 * MB);
  bf16* qh    = (bf16*)(ws + 32 * MB);  // 8MB; becomes ctx after attn
  bf16* kh    = (bf16*)(ws + 40 * MB);  // 8MB [B,NH,S,DKV]
  bf16* vperm = (bf16*)(ws + 48 * MB);  // 8MB PV-permuted V
  bf16* wot   = (bf16*)(ws + 56 * MB);  // 2MB (live until out-GEMM)
  float* Opart = (float*)(ws + 0 * MB); // 32MB fp32 partials (over qb..wvt)
  float* Lpart = (float*)(ws + 58 * MB);// 512KB row-sum partials
  bf16* ctx   = (bf16*)(ws + 32 * MB);  // 8MB (over qh)

  cast_qkv<<<dim3(2048, 3), 256, 0, stream>>>(query, key_, value, qb, kb, vb);
  transpose_w<<<dim3(32, 32, 4), dim3(32, 8), 0, stream>>>(Wq, Wk, Wv, Wo, wqt, wkt, wvt, wot);
  gemm_bt<128, 1><<<dim3(8, 32, 3), 256, 0, stream>>>(qb, kb, vb, wqt, wkt, wvt,
                                                      (void*)qh, (void*)kh, (void*)vperm,
                                                      4096, 1024, 1024);
  attn_kernel<<<dim3(16, 32, 2), 256, 0, stream>>>(qh, kh, vperm, mask, Opart, Lpart);
  combine_kernel<<<dim3(4096), 256, 0, stream>>>(Opart, Lpart, ctx);
  gemm_bt<64, 0><<<dim3(8, 64, 1), 256, 0, stream>>>(ctx, ctx, ctx, wot, wot, wot,
                                                     d_out, d_out, d_out,
                                                     4096, 1024, 1024);
}